// Round 1
// baseline (1640.382 us; speedup 1.0000x reference)
//
#include <hip/hip_runtime.h>
#include <math.h>

#define IMG_H 1080
#define IMG_W 1920
#define NPIX (IMG_H * IMG_W)

// Projection exactly mirroring the reference:
//   mc = means @ R^T + t ;  z>0.1 front test ; x = mc.x*fx/z_safe + cx ; bounds
__device__ __forceinline__ void project_pt(
    const float* __restrict__ vm, const float* __restrict__ Km,
    float mx, float my, float mz,
    float& x, float& y, float& z, bool& on)
{
    float mcx = vm[0] * mx + vm[1] * my + vm[2]  * mz + vm[3];
    float mcy = vm[4] * mx + vm[5] * my + vm[6]  * mz + vm[7];
    float mcz = vm[8] * mx + vm[9] * my + vm[10] * mz + vm[11];
    z = mcz;
    bool front = z > 0.1f;
    float z_safe = front ? z : 1.0f;
    float fx = Km[0], fy = Km[4], cx = Km[2], cy = Km[5];
    x = mcx * fx / z_safe + cx;
    y = mcy * fy / z_safe + cy;
    on = front && (x >= 0.0f) && (x < (float)(IMG_W - 1))
               && (y >= 0.0f) && (y < (float)(IMG_H - 1));
}

// Pass 1: scatter-min of z into zbuf at (y0,x0).
// z > 0.1 for all contributors, so uint-bit atomicMin == float min.
__global__ __launch_bounds__(256) void k_zmin(
    const float* __restrict__ means, const float* __restrict__ vm,
    const float* __restrict__ Km, unsigned int* __restrict__ zbuf, int N)
{
    int i = blockIdx.x * 256 + threadIdx.x;
    if (i >= N) return;
    float x, y, z; bool on;
    project_pt(vm, Km, means[3 * i], means[3 * i + 1], means[3 * i + 2], x, y, z, on);
    if (!on) return;
    int x0 = (int)floorf(x), y0 = (int)floorf(y);
    atomicMin(&zbuf[y0 * IMG_W + x0], __float_as_uint(z));
}

// Pass 2: vis test against zbuf, bilinear scatter-add of (r,g,b,z,w).
// NOTE: reference pairs wb=dx*(1-dy) with (y1,x0) and wc=(1-dx)*dy with (y0,x1).
__global__ __launch_bounds__(256) void k_splat(
    const float* __restrict__ means, const float* __restrict__ colors,
    const float* __restrict__ vm, const float* __restrict__ Km,
    const float* __restrict__ zbuf,
    float* __restrict__ acc /* NPIX*4, channels interleaved == output layout */,
    float* __restrict__ wsum /* NPIX */, int N)
{
    int i = blockIdx.x * 256 + threadIdx.x;
    if (i >= N) return;
    float x, y, z; bool on;
    project_pt(vm, Km, means[3 * i], means[3 * i + 1], means[3 * i + 2], x, y, z, on);
    if (!on) return;
    float x0f = floorf(x), y0f = floorf(y);
    int x0 = (int)x0f, y0 = (int)y0f;
    int pix = y0 * IMG_W + x0;
    if (!(z <= zbuf[pix] + 0.05f)) return;   // vis
    float dx = x - x0f, dy = y - y0f;
    float wa = (1.0f - dx) * (1.0f - dy);
    float wb = dx * (1.0f - dy);
    float wc = (1.0f - dx) * dy;
    float wd = dx * dy;
    float r = 1.0f / (1.0f + expf(-colors[3 * i]));
    float g = 1.0f / (1.0f + expf(-colors[3 * i + 1]));
    float b = 1.0f / (1.0f + expf(-colors[3 * i + 2]));
    // on==true guarantees x0<=W-2, y0<=H-2, so all four neighbors are in-bounds.
    int ia = pix;               // (y0,x0) <- wa
    int ib = pix + IMG_W;       // (y1,x0) <- wb   (reference's pairing)
    int ic = pix + 1;           // (y0,x1) <- wc
    int id = pix + IMG_W + 1;   // (y1,x1) <- wd
#define SPLAT1(idx, w)                                    \
    do {                                                  \
        atomicAdd(&acc[4 * (idx) + 0], r * (w));          \
        atomicAdd(&acc[4 * (idx) + 1], g * (w));          \
        atomicAdd(&acc[4 * (idx) + 2], b * (w));          \
        atomicAdd(&acc[4 * (idx) + 3], z * (w));          \
        atomicAdd(&wsum[(idx)], (w));                     \
    } while (0)
    SPLAT1(ia, wa);
    SPLAT1(ib, wb);
    SPLAT1(ic, wc);
    SPLAT1(id, wd);
#undef SPLAT1
}

// Pass 3: normalize in place (acc lives in d_out).
__global__ __launch_bounds__(256) void k_final(
    float* __restrict__ out, const float* __restrict__ wsum)
{
    int p = blockIdx.x * 256 + threadIdx.x;
    if (p >= NPIX) return;
    float tot = wsum[p] + 1e-6f;
    float4 v = reinterpret_cast<float4*>(out)[p];
    float r = v.x / tot, g = v.y / tot, b = v.z / tot, zz = v.w / tot;
    r = fminf(fmaxf(r, 0.0f), 1.0f);
    g = fminf(fmaxf(g, 0.0f), 1.0f);
    b = fminf(fmaxf(b, 0.0f), 1.0f);
    reinterpret_cast<float4*>(out)[p] = make_float4(r, g, b, zz);
}

extern "C" void kernel_launch(void* const* d_in, const int* in_sizes, int n_in,
                              void* d_out, int out_size, void* d_ws, size_t ws_size,
                              hipStream_t stream)
{
    const float* means  = (const float*)d_in[0];
    const float* colors = (const float*)d_in[1];
    const float* vm     = (const float*)d_in[5];   // viewmat 4x4 row-major
    const float* Km     = (const float*)d_in[6];   // K 3x3 row-major
    int N = in_sizes[0] / 3;

    // ws layout: [zbuf: NPIX u32][wsum: NPIX f32]  (~16.6 MB)
    unsigned int* zbuf = (unsigned int*)d_ws;
    float*        wsum = (float*)((char*)d_ws + (size_t)NPIX * 4);
    float*        out  = (float*)d_out;

    // inits (graph-capture safe). 0x7f7f7f7f = 3.39e38 acts as +inf: every
    // zbuf read happens at a pixel the reading gaussian itself min-wrote.
    hipMemsetAsync(zbuf, 0x7f, (size_t)NPIX * 4, stream);
    hipMemsetAsync(wsum, 0x00, (size_t)NPIX * 4, stream);
    hipMemsetAsync(out,  0x00, (size_t)NPIX * 16, stream);

    int nb = (N + 255) / 256;
    k_zmin <<<nb, 256, 0, stream>>>(means, vm, Km, zbuf, N);
    k_splat<<<nb, 256, 0, stream>>>(means, colors, vm, Km,
                                    (const float*)zbuf, out, wsum, N);
    k_final<<<(NPIX + 255) / 256, 256, 0, stream>>>(out, wsum);
}

// Round 2
// 596.392 us; speedup vs baseline: 2.7505x; 2.7505x over previous
//
#include <hip/hip_runtime.h>
#include <math.h>

#define IMG_H 1080
#define IMG_W 1920
#define NPIX (IMG_H * IMG_W)

// Tile grid for the binned fast path. 64x8 px tiles: 30 x 135 = 4050 tiles,
// 512 px/tile (exactly covers 1080x1920). LDS acc = 512 px * 5 ch * 4B = 10 KB.
#define TILE_W 64
#define TILE_H 8
#define NTX (IMG_W / TILE_W)   // 30
#define NTY (IMG_H / TILE_H)   // 135
#define NTILES (NTX * NTY)     // 4050
#define TPIX (TILE_W * TILE_H) // 512
#define CAP 2048               // slab slots per tile (worst-case est ~900)

// Projection exactly mirroring the reference:
//   mc = means @ R^T + t ;  z>0.1 front test ; x = mc.x*fx/z_safe + cx ; bounds
__device__ __forceinline__ void project_pt(
    const float* __restrict__ vm, const float* __restrict__ Km,
    float mx, float my, float mz,
    float& x, float& y, float& z, bool& on)
{
    float mcx = vm[0] * mx + vm[1] * my + vm[2]  * mz + vm[3];
    float mcy = vm[4] * mx + vm[5] * my + vm[6]  * mz + vm[7];
    float mcz = vm[8] * mx + vm[9] * my + vm[10] * mz + vm[11];
    z = mcz;
    bool front = z > 0.1f;
    float z_safe = front ? z : 1.0f;
    float fx = Km[0], fy = Km[4], cx = Km[2], cy = Km[5];
    x = mcx * fx / z_safe + cx;
    y = mcy * fy / z_safe + cy;
    on = front && (x >= 0.0f) && (x < (float)(IMG_W - 1))
               && (y >= 0.0f) && (y < (float)(IMG_H - 1));
}

// Pass 1: scatter-min of z into zbuf at (y0,x0).
// z > 0.1 for all contributors, so uint-bit atomicMin == float min.
__global__ __launch_bounds__(256) void k_zmin(
    const float* __restrict__ means, const float* __restrict__ vm,
    const float* __restrict__ Km, unsigned int* __restrict__ zbuf, int N)
{
    int i = blockIdx.x * 256 + threadIdx.x;
    if (i >= N) return;
    float x, y, z; bool on;
    project_pt(vm, Km, means[3 * i], means[3 * i + 1], means[3 * i + 2], x, y, z, on);
    if (!on) return;
    int x0 = (int)floorf(x), y0 = (int)floorf(y);
    atomicMin(&zbuf[y0 * IMG_W + x0], __float_as_uint(z));
}

// ---------------- FAST PATH: tile binning ----------------

// Pass 2: re-project, z-test, append gaussian index to each touched tile slab.
__global__ __launch_bounds__(256) void k_scatter(
    const float* __restrict__ means, const float* __restrict__ vm,
    const float* __restrict__ Km, const unsigned int* __restrict__ zbuf,
    unsigned int* __restrict__ cursors, unsigned int* __restrict__ records, int N)
{
    int i = blockIdx.x * 256 + threadIdx.x;
    if (i >= N) return;
    float x, y, z; bool on;
    project_pt(vm, Km, means[3 * i], means[3 * i + 1], means[3 * i + 2], x, y, z, on);
    if (!on) return;
    int x0 = (int)floorf(x), y0 = (int)floorf(y);
    int pix = y0 * IMG_W + x0;
    if (!(z <= __uint_as_float(zbuf[pix]) + 0.05f)) return;   // vis cull (~50%)
    // footprint touches pixels (x0..x0+1, y0..y0+1); on==true => all in-bounds
    int tx0 = x0 / TILE_W, ty0 = y0 / TILE_H;
    int tx1 = (x0 + 1) / TILE_W, ty1 = (y0 + 1) / TILE_H;
#pragma unroll
    for (int sy = 0; sy < 2; ++sy) {
        int ty = sy ? ty1 : ty0;
        if (sy && ty1 == ty0) continue;
#pragma unroll
        for (int sx = 0; sx < 2; ++sx) {
            int tx = sx ? tx1 : tx0;
            if (sx && tx1 == tx0) continue;
            int t = ty * NTX + tx;
            unsigned int slot = atomicAdd(&cursors[t], 1u);
            if (slot < CAP) records[(size_t)t * CAP + slot] = (unsigned int)i;
        }
    }
}

// Pass 3: one block per tile. Gather records, recompute projection+sigmoid,
// accumulate 4-corner bilinear splat into LDS, normalize, write float4 out.
__global__ __launch_bounds__(256) void k_tile(
    const float* __restrict__ means, const float* __restrict__ colors,
    const float* __restrict__ vm, const float* __restrict__ Km,
    const unsigned int* __restrict__ cursors,
    const unsigned int* __restrict__ records,
    float* __restrict__ out)
{
    __shared__ float sR[TPIX], sG[TPIX], sB[TPIX], sZ[TPIX], sW[TPIX];
    int tid = threadIdx.x;
    int t = blockIdx.x;
    int txb = (t % NTX) * TILE_W;   // tile origin x
    int tyb = (t / NTX) * TILE_H;   // tile origin y
    for (int p = tid; p < TPIX; p += 256) {
        sR[p] = 0.0f; sG[p] = 0.0f; sB[p] = 0.0f; sZ[p] = 0.0f; sW[p] = 0.0f;
    }
    __syncthreads();

    int cnt = (int)min(cursors[t], (unsigned int)CAP);
    const unsigned int* rec = records + (size_t)t * CAP;
    for (int j = tid; j < cnt; j += 256) {
        int i = (int)rec[j];
        float x, y, z; bool on;
        project_pt(vm, Km, means[3 * i], means[3 * i + 1], means[3 * i + 2], x, y, z, on);
        float x0f = floorf(x), y0f = floorf(y);
        int x0 = (int)x0f, y0 = (int)y0f;
        float dx = x - x0f, dy = y - y0f;
        float wa = (1.0f - dx) * (1.0f - dy);
        float wb = dx * (1.0f - dy);
        float wc = (1.0f - dx) * dy;
        float wd = dx * dy;
        float r = 1.0f / (1.0f + expf(-colors[3 * i]));
        float g = 1.0f / (1.0f + expf(-colors[3 * i + 1]));
        float b = 1.0f / (1.0f + expf(-colors[3 * i + 2]));
        // reference pairing: wa->(y0,x0)  wb->(y1,x0)  wc->(y0,x1)  wd->(y1,x1)
        int cxs[4] = { x0, x0, x0 + 1, x0 + 1 };
        int cys[4] = { y0, y0 + 1, y0, y0 + 1 };
        float ws[4] = { wa, wb, wc, wd };
#pragma unroll
        for (int c = 0; c < 4; ++c) {
            int lx = cxs[c] - txb, ly = cys[c] - tyb;
            if ((unsigned)lx < TILE_W && (unsigned)ly < TILE_H) {
                int lp = ly * TILE_W + lx;
                float w = ws[c];
                atomicAdd(&sR[lp], r * w);
                atomicAdd(&sG[lp], g * w);
                atomicAdd(&sB[lp], b * w);
                atomicAdd(&sZ[lp], z * w);
                atomicAdd(&sW[lp], w);
            }
        }
    }
    __syncthreads();

    for (int p = tid; p < TPIX; p += 256) {
        float tot = sW[p] + 1e-6f;
        float r = sR[p] / tot, g = sG[p] / tot, b = sB[p] / tot, zz = sZ[p] / tot;
        r = fminf(fmaxf(r, 0.0f), 1.0f);
        g = fminf(fmaxf(g, 0.0f), 1.0f);
        b = fminf(fmaxf(b, 0.0f), 1.0f);
        int gy = tyb + p / TILE_W, gx = txb + p % TILE_W;
        reinterpret_cast<float4*>(out)[gy * IMG_W + gx] = make_float4(r, g, b, zz);
    }
}

// ---------------- FALLBACK PATH (round-1, proven, 16.6 MB ws) ----------------

__global__ __launch_bounds__(256) void k_splat(
    const float* __restrict__ means, const float* __restrict__ colors,
    const float* __restrict__ vm, const float* __restrict__ Km,
    const float* __restrict__ zbuf,
    float* __restrict__ acc, float* __restrict__ wsum, int N)
{
    int i = blockIdx.x * 256 + threadIdx.x;
    if (i >= N) return;
    float x, y, z; bool on;
    project_pt(vm, Km, means[3 * i], means[3 * i + 1], means[3 * i + 2], x, y, z, on);
    if (!on) return;
    float x0f = floorf(x), y0f = floorf(y);
    int x0 = (int)x0f, y0 = (int)y0f;
    int pix = y0 * IMG_W + x0;
    if (!(z <= zbuf[pix] + 0.05f)) return;
    float dx = x - x0f, dy = y - y0f;
    float wa = (1.0f - dx) * (1.0f - dy);
    float wb = dx * (1.0f - dy);
    float wc = (1.0f - dx) * dy;
    float wd = dx * dy;
    float r = 1.0f / (1.0f + expf(-colors[3 * i]));
    float g = 1.0f / (1.0f + expf(-colors[3 * i + 1]));
    float b = 1.0f / (1.0f + expf(-colors[3 * i + 2]));
    int ia = pix, ib = pix + IMG_W, ic = pix + 1, id = pix + IMG_W + 1;
#define SPLAT1(idx, w)                                    \
    do {                                                  \
        atomicAdd(&acc[4 * (idx) + 0], r * (w));          \
        atomicAdd(&acc[4 * (idx) + 1], g * (w));          \
        atomicAdd(&acc[4 * (idx) + 2], b * (w));          \
        atomicAdd(&acc[4 * (idx) + 3], z * (w));          \
        atomicAdd(&wsum[(idx)], (w));                     \
    } while (0)
    SPLAT1(ia, wa); SPLAT1(ib, wb); SPLAT1(ic, wc); SPLAT1(id, wd);
#undef SPLAT1
}

__global__ __launch_bounds__(256) void k_final(
    float* __restrict__ out, const float* __restrict__ wsum)
{
    int p = blockIdx.x * 256 + threadIdx.x;
    if (p >= NPIX) return;
    float tot = wsum[p] + 1e-6f;
    float4 v = reinterpret_cast<float4*>(out)[p];
    float r = v.x / tot, g = v.y / tot, b = v.z / tot, zz = v.w / tot;
    r = fminf(fmaxf(r, 0.0f), 1.0f);
    g = fminf(fmaxf(g, 0.0f), 1.0f);
    b = fminf(fmaxf(b, 0.0f), 1.0f);
    reinterpret_cast<float4*>(out)[p] = make_float4(r, g, b, zz);
}

extern "C" void kernel_launch(void* const* d_in, const int* in_sizes, int n_in,
                              void* d_out, int out_size, void* d_ws, size_t ws_size,
                              hipStream_t stream)
{
    const float* means  = (const float*)d_in[0];
    const float* colors = (const float*)d_in[1];
    const float* vm     = (const float*)d_in[5];   // viewmat 4x4 row-major
    const float* Km     = (const float*)d_in[6];   // K 3x3 row-major
    int N = in_sizes[0] / 3;
    float* out = (float*)d_out;
    int nb = (N + 255) / 256;

    const size_t zbufB = (size_t)NPIX * 4;
    const size_t curB  = (size_t)NTILES * 4;
    const size_t recB  = (size_t)NTILES * CAP * 4;
    const size_t need  = zbufB + curB + recB;   // ~41.5 MB

    if (ws_size >= need) {
        // ---- fast path: tile-binned, LDS accumulation, no global atomicAdds
        unsigned int* zbuf    = (unsigned int*)d_ws;
        unsigned int* cursors = (unsigned int*)((char*)d_ws + zbufB);
        unsigned int* records = (unsigned int*)((char*)d_ws + zbufB + curB);
        hipMemsetAsync(zbuf, 0x7f, zbufB, stream);   // 3.39e38 acts as +inf
        hipMemsetAsync(cursors, 0, curB, stream);
        k_zmin   <<<nb, 256, 0, stream>>>(means, vm, Km, zbuf, N);
        k_scatter<<<nb, 256, 0, stream>>>(means, vm, Km, zbuf, cursors, records, N);
        k_tile   <<<NTILES, 256, 0, stream>>>(means, colors, vm, Km,
                                              cursors, records, out);
    } else {
        // ---- fallback: round-1 global-atomic pipeline (16.6 MB ws)
        unsigned int* zbuf = (unsigned int*)d_ws;
        float*        wsum = (float*)((char*)d_ws + zbufB);
        hipMemsetAsync(zbuf, 0x7f, zbufB, stream);
        hipMemsetAsync(wsum, 0x00, zbufB, stream);
        hipMemsetAsync(out,  0x00, (size_t)NPIX * 16, stream);
        k_zmin <<<nb, 256, 0, stream>>>(means, vm, Km, zbuf, N);
        k_splat<<<nb, 256, 0, stream>>>(means, colors, vm, Km,
                                        (const float*)zbuf, out, wsum, N);
        k_final<<<(NPIX + 255) / 256, 256, 0, stream>>>(out, wsum);
    }
}